// Round 8
// baseline (1426.818 us; speedup 1.0000x reference)
//
#include <hip/hip_runtime.h>
#include <hip/hip_bf16.h>
#include <hip/hip_cooperative_groups.h>
#include <math.h>

namespace cg = cooperative_groups;

// Problem constants (fixed by reference setup_inputs)
#define BB 16
#define NN 64
#define ATTR 4
#define STATE 16
#define RELD 9
#define GG 32
#define NF 256
#define NROWS_OBJ (BB*NN)        // 1024
#define NROWS_REL (BB*NN*NN)     // 65536

typedef _Float16 half8 __attribute__((ext_vector_type(8)));
typedef _Float16 half4 __attribute__((ext_vector_type(4)));
typedef float  floatx4 __attribute__((ext_vector_type(4)));

// fp16 split: x ~= h + l, |x-(h+l)| ~ 2^-22 |x| (A-operand use only)
__device__ __forceinline__ void split2h(float x, _Float16& h, _Float16& l) {
  h = (_Float16)x;
  l = (_Float16)(x - (float)h);
}

#define F0_ELEMS (2 * 16 * 64 * 8)   // 16384
#define F1_ELEMS (8 * 16 * 64 * 8)   // 65536
#define F_TOTAL  (F0_ELEMS + 2 * F1_ELEMS)

#define ROWS 32
#define NRT 2
#define HSTR 264
#define XSTR 72

// ---------------------------------------------------------------------------
// Frozen rel tile body (R15 form, measured 58-62 us standalone).  Extracted
// as a device function so the cooperative mega-kernel and the fallback
// standalone kernel share one implementation.
// ---------------------------------------------------------------------------
#define ZERO_ACC() do { \
  _Pragma("unroll") for (int rt = 0; rt < NRT; ++rt) \
  _Pragma("unroll") for (int ct = 0; ct < 4; ++ct) acc[rt][ct] = (floatx4)(0.f); } while (0)

#define STAGE(Sn, AH, AL, ASTR, BF) do { \
  half8 ah[2][NRT], al[2][NRT], bf[2][4]; \
  _Pragma("unroll") for (int ct = 0; ct < 4; ++ct) \
    bf[0][ct] = *(const half8*)((BF) + (size_t)((wave * 4 + ct) * 64 + lane) * 8); \
  _Pragma("unroll") for (int rt = 0; rt < NRT; ++rt) { \
    ah[0][rt] = *(const half8*)(&(AH)[(rt * 16 + l16) * (ASTR) + quad * 8]); \
    al[0][rt] = *(const half8*)(&(AL)[(rt * 16 + l16) * (ASTR) + quad * 8]); } \
  _Pragma("unroll") \
  for (int s = 0; s < (Sn); ++s) { \
    int cur = s & 1, nxt = cur ^ 1; \
    if (s + 1 < (Sn)) { \
      _Pragma("unroll") for (int ct = 0; ct < 4; ++ct) \
        bf[nxt][ct] = *(const half8*)((BF) + (size_t)(((s + 1) * 16 + wave * 4 + ct) * 64 + lane) * 8); \
      _Pragma("unroll") for (int rt = 0; rt < NRT; ++rt) { \
        ah[nxt][rt] = *(const half8*)(&(AH)[(rt * 16 + l16) * (ASTR) + (s + 1) * 32 + quad * 8]); \
        al[nxt][rt] = *(const half8*)(&(AL)[(rt * 16 + l16) * (ASTR) + (s + 1) * 32 + quad * 8]); } } \
    _Pragma("unroll") for (int rt = 0; rt < NRT; ++rt) \
    _Pragma("unroll") for (int ct = 0; ct < 4; ++ct) { \
      acc[rt][ct] = __builtin_amdgcn_mfma_f32_16x16x32_f16(ah[cur][rt], bf[cur][ct], acc[rt][ct], 0, 0, 0); \
      acc[rt][ct] = __builtin_amdgcn_mfma_f32_16x16x32_f16(al[cur][rt], bf[cur][ct], acc[rt][ct], 0, 0, 0); } \
  } } while (0)

__device__ __forceinline__ void rel_tile(
    _Float16* S, int tid, int row0,
    const float* __restrict__ attrs, const float* __restrict__ states,
    const float* __restrict__ rel_attrs,
    const _Float16* __restrict__ F0, const float* __restrict__ b0,
    const _Float16* __restrict__ F1, const float* __restrict__ b1,
    const _Float16* __restrict__ F2,
    const float* __restrict__ Q, const float* __restrict__ R,
    _Float16* __restrict__ P, float* __restrict__ part)
{
  _Float16* Hh = S;
  _Float16* Hl = S + ROWS * HSTR;
  _Float16* Xh = Hh;   // X aliased onto H (dead after stage 1)
  _Float16* Xl = Hl;

  int wave = tid >> 6;
  int lane = tid & 63;
  int quad = lane >> 4;
  int l16  = lane & 15;

  for (int idx = tid; idx < ROWS * 64; idx += 256) {
    int r = idx >> 6, k = idx & 63;
    int grow = row0 + r;
    int j = grow & 63, i = (grow >> 6) & 63, b = grow >> 12;
    float v = 0.f;
    if (k < RELD)                     v = rel_attrs[(size_t)grow * RELD + k];
    else if (k < RELD + STATE)        v = states[(b * NN + i) * STATE + (k - RELD)]
                                        - states[(b * NN + j) * STATE + (k - RELD)];
    else if (k < RELD + STATE + ATTR) v = attrs[(b * NN + i) * ATTR + (k - RELD - STATE)];
    else if (k < 33)                  v = attrs[(b * NN + j) * ATTR + (k - RELD - STATE - ATTR)];
    _Float16 h, l; split2h(v, h, l);
    Xh[r * XSTR + k] = h;
    Xl[r * XSTR + k] = l;
  }
  __syncthreads();

  floatx4 acc[NRT][4];

  // ---- stage 1: H = ReLU(X @ W0 + b0), K=64 (padded)
  ZERO_ACC();
  STAGE(2, Xh, Xl, XSTR, F0);
  __syncthreads();  // X reads done before H overwrites the aliased region
#pragma unroll
  for (int ct = 0; ct < 4; ++ct) {
    int col = wave * 64 + ct * 16 + l16;
    float bias = b0[col];
#pragma unroll
    for (int rt = 0; rt < NRT; ++rt)
#pragma unroll
      for (int r = 0; r < 4; ++r) {
        int row = rt * 16 + quad * 4 + r;
        float h = fmaxf(acc[rt][ct][r] + bias, 0.f);
        split2h(h, Hh[row * HSTR + col], Hl[row * HSTR + col]);
      }
  }
  __syncthreads();

  // ---- stage 2: E = ReLU(H @ W1 + b1), K=256
  ZERO_ACC();
  STAGE(8, Hh, Hl, HSTR, F1);
  __syncthreads();
#pragma unroll
  for (int ct = 0; ct < 4; ++ct) {
    int col = wave * 64 + ct * 16 + l16;
    float bias = b1[col];
#pragma unroll
    for (int rt = 0; rt < NRT; ++rt)
#pragma unroll
      for (int r = 0; r < 4; ++r) {
        int row = rt * 16 + quad * 4 + r;
        float e = fmaxf(acc[rt][ct][r] + bias, 0.f);
        split2h(e, Hh[row * HSTR + col], Hl[row * HSTR + col]);
      }
  }
  __syncthreads();

  // ---- stage 3: P-tile in registers (K=256)
  ZERO_ACC();
  STAGE(8, Hh, Hl, HSTR, F2);

  // ---- store P fp16 (pstep 2 reads it in the sweep)
#pragma unroll
  for (int ct = 0; ct < 4; ++ct) {
    int col = wave * 64 + ct * 16 + l16;
#pragma unroll
    for (int rt = 0; rt < NRT; ++rt)
#pragma unroll
      for (int r = 0; r < 4; ++r) {
        int row = rt * 16 + quad * 4 + r;
        P[(size_t)(row0 + row) * NF + col] = (_Float16)acc[rt][ct][r];
      }
  }
  __syncthreads();                       // all E reads done — LDS reusable

  // ---- fused pstep-1 aggregation epilogue (exact fp32 acc)
  {
    float* Rs = (float*)S;               // 32 x 256 fp32 R-tile (32KB)
    int bi    = row0 >> 6;
    int jbase = row0 & 63;               // 0 or 32
    int b     = row0 >> 12;
    for (int idx = tid; idx < ROWS * NF; idx += 256) {
      int rr = idx >> 8, cc = idx & 255;
      Rs[idx] = R[(size_t)(b * NN + jbase + rr) * NF + cc];
    }
    __syncthreads();
#pragma unroll
    for (int ct = 0; ct < 4; ++ct) {
      int col = wave * 64 + ct * 16 + l16;
      float q = Q[bi * NF + col];
      float s = 0.f;
#pragma unroll
      for (int rt = 0; rt < NRT; ++rt)
#pragma unroll
        for (int r = 0; r < 4; ++r) {
          int row = rt * 16 + quad * 4 + r;
          s += fmaxf(acc[rt][ct][r] + q + Rs[row * NF + col], 0.f);
        }
      s += __shfl_xor(s, 16, 64);        // quad butterfly: rows 0..31 summed
      s += __shfl_xor(s, 32, 64);
      if (quad == 0)
        part[((size_t)bi * 2 + (jbase >> 5)) * NF + col] = s;
    }
  }
}
#undef ZERO_ACC
#undef STAGE

// ---------------------------------------------------------------------------
// R23: ONE cooperative mega-kernel.  R22 measured ~15-20 us fixed cost per
// dependent dispatch; R20/R21 measured ~25 GB/s/CU on unique bytes.  The
// winning structure: 16x16-tiled obj phases (16-32 KB unique/block) inside
// a single dispatch with grid.sync() phase barriers.  Geometry 1024 x 256
// is exactly co-resident (LDS 33792 -> 4 blocks/CU; launch_bounds(256,4)
// caps VGPR at 128).  rel runs as a phase, 2 row-tiles per block —
// identical occupancy/code to the frozen standalone.
// ---------------------------------------------------------------------------
struct MegaArgs {
  const float *attrs, *states, *rel_attrs;
  const float *enc_w0, *enc_b0, *enc_w1, *enc_b1;
  const float *rel_b0, *rel_b1;
  const float *rel_w0, *rel_w1;
  const float *rp_w, *rp_b, *pp_w, *pp_b;
  const float *pred_w0, *pred_b0, *pred_w1, *pred_b1;
  _Float16 *F0, *F1, *F2, *P;
  float *obj0, *obj1, *Q0, *R0, *Q1, *R1, *part1, *out;
};

__global__ __launch_bounds__(256, 4) void mega_kernel(MegaArgs a)
{
  cg::grid_group grid = cg::this_grid();
  __shared__ __align__(16) _Float16 S[2 * ROWS * HSTR];   // 33792 B
  int tid = threadIdx.x, bid = blockIdx.x;

  // ---- A: F-prep (single pass; 262144 threads >= F_TOTAL)
  {
    int idx = bid * 256 + tid;
    if (idx < F0_ELEMS) {
      int j = idx & 7, lane = (idx >> 3) & 63, g = (idx >> 9) & 15, s = idx >> 13;
      int k = s * 32 + (lane >> 4) * 8 + j, n = g * 16 + (lane & 15);
      float v = (k < 33) ? a.rel_w0[k * NF + n] : 0.f;
      a.F0[idx] = (_Float16)v;
    } else if (idx < F0_ELEMS + F1_ELEMS) {
      int t = idx - F0_ELEMS;
      int j = t & 7, lane = (t >> 3) & 63, g = (t >> 9) & 15, s = t >> 13;
      int k = s * 32 + (lane >> 4) * 8 + j, n = g * 16 + (lane & 15);
      a.F1[t] = (_Float16)a.rel_w1[k * NF + n];
    } else if (idx < F_TOTAL) {
      int t = idx - (F0_ELEMS + F1_ELEMS);
      int j = t & 7, lane = (t >> 3) & 63, g = (t >> 9) & 15, s = t >> 13;
      int k = s * 32 + (lane >> 4) * 8 + j, n = g * 16 + (lane & 15);
      a.F2[t] = (_Float16)a.rp_w[k * NF + n];
    }
  }

  // ---- B: enc H (redundant 16-row tile in LDS, K=20) + obj0 16x16 tile
  {
    float* Hs = (float*)S;            // 16 x 260 fp32 = 16.6 KB
    int mt = bid >> 4, nt = bid & 15;
    int row0 = mt * 16;
    for (int t = 0; t < 16; ++t) {
      int idx = t * 256 + tid;
      int r = idx >> 8, cc = idx & 255;
      int m = row0 + r;
      float v = a.enc_b0[cc];
#pragma unroll
      for (int k = 0; k < 20; ++k) {
        float x = (k < ATTR) ? a.attrs[m * ATTR + k] : a.states[m * STATE + (k - ATTR)];
        v += x * a.enc_w0[k * NF + cc];
      }
      Hs[r * 260 + cc] = fmaxf(v, 0.f);
    }
    __syncthreads();
    int r = tid >> 4, c = tid & 15;
    int col = nt * 16 + c;
    float acc = a.enc_b1[col];
#pragma unroll 8
    for (int k = 0; k < 256; ++k)
      acc += Hs[r * 260 + k] * a.enc_w1[(size_t)k * NF + col];
    a.obj0[(size_t)(row0 + r) * NF + col] = fmaxf(acc, 0.f);
    __syncthreads();                    // Hs reads done before rel reuses S
  }
  grid.sync();

  // ---- C: Q0 | R0 (2048 tiles of 16x16, 2 per block)
#pragma unroll
  for (int t = 0; t < 2; ++t) {
    int tt = bid + t * 1024;
    int mt = tt >> 5, ntc = tt & 31;
    int row = mt * 16 + (tid >> 4);
    int c512 = ntc * 16 + (tid & 15);
    const float* Arow = a.obj0 + (size_t)row * NF;
    if (c512 < 256) {
      float acc = a.rp_b[c512];
      const float* W = a.rp_w + 256 * NF + c512;
#pragma unroll 8
      for (int k = 0; k < 256; ++k) acc += Arow[k] * W[(size_t)k * NF];
      a.Q0[(size_t)row * NF + c512] = acc;
    } else {
      float acc = 0.f;
      const float* W = a.rp_w + 512 * NF + (c512 - 256);
#pragma unroll 8
      for (int k = 0; k < 256; ++k) acc += Arow[k] * W[(size_t)k * NF];
      a.R0[(size_t)row * NF + (c512 - 256)] = acc;
    }
  }
  grid.sync();

  // ---- D: rel chain, 2 row-tiles per block (frozen body)
  for (int it = 0; it < 2; ++it) {
    rel_tile(S, tid, (it * 1024 + bid) * ROWS,
             a.attrs, a.states, a.rel_attrs, a.F0, a.rel_b0, a.F1, a.rel_b1,
             a.F2, a.Q0, a.R0, a.P, a.part1);
    __syncthreads();
  }
  grid.sync();

  // ---- E: upd1 -> obj1   (K = 512: [obj0 | part-pair-sum] @ pp_w)
  {
    int mt = bid >> 4, nt = bid & 15;
    int row = mt * 16 + (tid >> 4);
    int col = nt * 16 + (tid & 15);
    float acc = a.pp_b[col];
    const float* Ao = a.obj0 + (size_t)row * NF;
    const float* W1 = a.pp_w + col;
#pragma unroll 8
    for (int k = 0; k < 256; ++k) acc += Ao[k] * W1[(size_t)k * NF];
    const float* G0 = a.part1 + (size_t)row * 2 * NF;
    const float* W2 = a.pp_w + (size_t)256 * NF + col;
#pragma unroll 8
    for (int k = 0; k < 256; ++k) acc += (G0[k] + G0[NF + k]) * W2[(size_t)k * NF];
    a.obj1[(size_t)row * NF + col] = fmaxf(acc, 0.f);
  }
  grid.sync();

  // ---- F: Q1 | R1
#pragma unroll
  for (int t = 0; t < 2; ++t) {
    int tt = bid + t * 1024;
    int mt = tt >> 5, ntc = tt & 31;
    int row = mt * 16 + (tid >> 4);
    int c512 = ntc * 16 + (tid & 15);
    const float* Arow = a.obj1 + (size_t)row * NF;
    if (c512 < 256) {
      float acc = a.rp_b[c512];
      const float* W = a.rp_w + 256 * NF + c512;
#pragma unroll 8
      for (int k = 0; k < 256; ++k) acc += Arow[k] * W[(size_t)k * NF];
      a.Q1[(size_t)row * NF + c512] = acc;
    } else {
      float acc = 0.f;
      const float* W = a.rp_w + 512 * NF + (c512 - 256);
#pragma unroll 8
      for (int k = 0; k < 256; ++k) acc += Arow[k] * W[(size_t)k * NF];
      a.R1[(size_t)row * NF + (c512 - 256)] = acc;
    }
  }
  grid.sync();

  // ---- G: pstep-2 sweep -> G2 (overlays part1; part1 consumed in E)
  {
    int mt = bid >> 4, nt = bid & 15;
    int i = mt * 16 + (tid >> 4);
    int col = nt * 16 + (tid & 15);
    int b = i >> 6;
    float q = a.Q1[(size_t)i * NF + col];
    const _Float16* Pb = a.P + (size_t)i * NN * NF + col;
    const float* Rb = a.R1 + (size_t)(b * NN) * NF + col;
    float s = 0.f;
#pragma unroll 8
    for (int j = 0; j < NN; ++j)
      s += fmaxf((float)Pb[(size_t)j * NF] + q + Rb[(size_t)j * NF], 0.f);
    a.part1[(size_t)i * NF + col] = s;
  }
  grid.sync();

  // ---- H: upd2 -> obj2 (overlays obj0; obj0 consumed in E)
  {
    int mt = bid >> 4, nt = bid & 15;
    int row = mt * 16 + (tid >> 4);
    int col = nt * 16 + (tid & 15);
    float acc = a.pp_b[col];
    const float* Ao = a.obj1 + (size_t)row * NF;
    const float* W1 = a.pp_w + col;
#pragma unroll 8
    for (int k = 0; k < 256; ++k) acc += Ao[k] * W1[(size_t)k * NF];
    const float* G2 = a.part1 + (size_t)row * NF;
    const float* W2 = a.pp_w + (size_t)256 * NF + col;
#pragma unroll 8
    for (int k = 0; k < 256; ++k) acc += G2[k] * W2[(size_t)k * NF];
    a.obj0[(size_t)row * NF + col] = fmaxf(acc, 0.f);
  }
  grid.sync();

  // ---- I: pred1 -> T (overlays Q0; Q0 consumed in D)
  {
    int mt = bid >> 4, nt = bid & 15;
    int row = mt * 16 + (tid >> 4);
    int col = nt * 16 + (tid & 15);
    float acc = a.pred_b0[col];
    const float* Ao = a.obj0 + (size_t)row * NF;
    const float* W = a.pred_w0 + col;
#pragma unroll 8
    for (int k = 0; k < 256; ++k) acc += Ao[k] * W[(size_t)k * NF];
    a.Q0[(size_t)row * NF + col] = fmaxf(acc, 0.f);
  }
  grid.sync();

  // ---- J: pred2 -> out (128 tiles; others idle)
  if (bid < 128) {
    int mt = bid >> 1, nt = bid & 1;
    int row = mt * 16 + (tid >> 4);
    int col = nt * 16 + (tid & 15);
    float acc = a.pred_b1[col];
    const float* T = a.Q0 + (size_t)row * NF;
#pragma unroll 8
    for (int k = 0; k < 256; ++k) acc += T[k] * a.pred_w1[k * GG + col];
    a.out[(size_t)row * GG + col] = tanhf(acc);
  }
}

// ===========================================================================
// FALLBACK PATH — exact R21 kernels (proven 186.8 us) used only if the
// cooperative launch is rejected by the runtime/capture.
// ===========================================================================
__device__ __forceinline__ float4 gemm4_k64(const float* __restrict__ W,
                                            const float* A,
                                            int kseg, int rsel, int c4)
{
  float4 p = make_float4(0.f, 0.f, 0.f, 0.f);
  int k0 = kseg * 64;
#pragma unroll 8
  for (int k = 0; k < 64; ++k) {
    float4 w = *(const float4*)(W + (size_t)(k0 + k) * NF + c4);
    float a = A[rsel * NF + k0 + k];
    p.x += a * w.x; p.y += a * w.y; p.z += a * w.z; p.w += a * w.w;
  }
  return p;
}

__global__ __launch_bounds__(256, 4) void rel_agg_store_mfma(
    const float* __restrict__ attrs, const float* __restrict__ states,
    const float* __restrict__ rel_attrs,
    const _Float16* __restrict__ F0, const float* __restrict__ b0,
    const _Float16* __restrict__ F1, const float* __restrict__ b1,
    const _Float16* __restrict__ F2,
    const float* __restrict__ Q, const float* __restrict__ R,
    _Float16* __restrict__ P, float* __restrict__ part)
{
  __shared__ __align__(16) _Float16 S[2 * ROWS * HSTR];
  rel_tile(S, threadIdx.x, blockIdx.x * ROWS,
           attrs, states, rel_attrs, F0, b0, F1, b1, F2, Q, R, P, part);
}

__global__ __launch_bounds__(1024) void enc_qr_prep_kernel(
    const float* __restrict__ attrs, const float* __restrict__ states,
    const float* __restrict__ w0, const float* __restrict__ b0,
    const float* __restrict__ w1, const float* __restrict__ b1,
    const float* __restrict__ rpw, const float* __restrict__ rpb,
    const float* __restrict__ rel_w0, const float* __restrict__ rel_w1,
    _Float16* __restrict__ F0, _Float16* __restrict__ F1,
    _Float16* __restrict__ F2,
    float* __restrict__ obj, float* __restrict__ Q, float* __restrict__ R)
{
  int tid = threadIdx.x;
  for (int idx = blockIdx.x * 1024 + tid; idx < F_TOTAL; idx += 256 * 1024) {
    if (idx < F0_ELEMS) {
      int j = idx & 7, lane = (idx >> 3) & 63, g = (idx >> 9) & 15, s = idx >> 13;
      int k = s * 32 + (lane >> 4) * 8 + j, n = g * 16 + (lane & 15);
      float v = (k < 33) ? rel_w0[k * NF + n] : 0.f;
      F0[idx] = (_Float16)v;
    } else if (idx < F0_ELEMS + F1_ELEMS) {
      int t = idx - F0_ELEMS;
      int j = t & 7, lane = (t >> 3) & 63, g = (t >> 9) & 15, s = t >> 13;
      int k = s * 32 + (lane >> 4) * 8 + j, n = g * 16 + (lane & 15);
      F1[t] = (_Float16)rel_w1[k * NF + n];
    } else {
      int t = idx - (F0_ELEMS + F1_ELEMS);
      int j = t & 7, lane = (t >> 3) & 63, g = (t >> 9) & 15, s = t >> 13;
      int k = s * 32 + (lane >> 4) * 8 + j, n = g * 16 + (lane & 15);
      F2[t] = (_Float16)rpw[k * NF + n];
    }
  }
  __shared__ float X[4 * 20];
  __shared__ float HO[4 * NF];
  __shared__ __align__(16) float red[16 * 4 * NF];
  int row0 = blockIdx.x * 4;
  if (tid < 80) {
    int r = tid / 20, k = tid % 20;
    int m = row0 + r;
    X[tid] = (k < ATTR) ? attrs[m * ATTR + k] : states[m * STATE + (k - ATTR)];
  }
  __syncthreads();
  int wv = tid >> 6, lane = tid & 63, c4 = lane * 4;
  int rq = tid >> 8, c = tid & 255;
  {
    float a = b0[c];
#pragma unroll
    for (int k = 0; k < 20; ++k) a += X[rq * 20 + k] * w0[k * NF + c];
    HO[rq * NF + c] = fmaxf(a, 0.f);
  }
  __syncthreads();
  {
    floatx4 w[16];
#pragma unroll
    for (int k = 0; k < 16; ++k)
      w[k] = *(const floatx4*)(w1 + (size_t)(wv * 16 + k) * NF + c4);
    floatx4 acc[4] = {(floatx4)(0.f), (floatx4)(0.f), (floatx4)(0.f), (floatx4)(0.f)};
#pragma unroll
    for (int k = 0; k < 16; ++k) {
      int kk = wv * 16 + k;
#pragma unroll
      for (int r = 0; r < 4; ++r) acc[r] += HO[r * NF + kk] * w[k];
    }
#pragma unroll
    for (int r = 0; r < 4; ++r)
      *(floatx4*)(&red[(size_t)(wv * 4 + r) * NF + c4]) = acc[r];
  }
  __syncthreads();
  {
    float a = b1[c];
#pragma unroll
    for (int ks = 0; ks < 16; ++ks) a += red[(size_t)(ks * 4 + rq) * NF + c];
    a = fmaxf(a, 0.f);
    HO[rq * NF + c] = a;
    obj[(row0 + rq) * NF + c] = a;
  }
  __syncthreads();
  {
    const float* W = (wv < 8) ? (rpw + 256 * NF) : (rpw + 512 * NF);
    int k0 = (wv & 7) * 32;
    floatx4 acc[4] = {(floatx4)(0.f), (floatx4)(0.f), (floatx4)(0.f), (floatx4)(0.f)};
#pragma unroll
    for (int kb = 0; kb < 2; ++kb) {
      floatx4 w[16];
#pragma unroll
      for (int k = 0; k < 16; ++k)
        w[k] = *(const floatx4*)(W + (size_t)(k0 + kb * 16 + k) * NF + c4);
#pragma unroll
      for (int k = 0; k < 16; ++k) {
        int kk = k0 + kb * 16 + k;
#pragma unroll
        for (int r = 0; r < 4; ++r) acc[r] += HO[r * NF + kk] * w[k];
      }
    }
#pragma unroll
    for (int r = 0; r < 4; ++r)
      *(floatx4*)(&red[(size_t)(wv * 4 + r) * NF + c4]) = acc[r];
  }
  __syncthreads();
  {
    float q = rpb[c];
#pragma unroll
    for (int ks = 0; ks < 8; ++ks) q += red[(size_t)(ks * 4 + rq) * NF + c];
    float rr = 0.f;
#pragma unroll
    for (int ks = 8; ks < 16; ++ks) rr += red[(size_t)(ks * 4 + rq) * NF + c];
    Q[(row0 + rq) * NF + c] = q;
    R[(row0 + rq) * NF + c] = rr;
  }
}

__global__ __launch_bounds__(1024) void upd_qr_kernel(
    const float* __restrict__ part, const float* __restrict__ obj,
    const float* __restrict__ ppw, const float* __restrict__ ppb,
    const float* __restrict__ rpw, const float* __restrict__ rpb,
    float* __restrict__ obj_out, float* __restrict__ Qo, float* __restrict__ Ro)
{
  __shared__ float AG[4 * 512];
  __shared__ __align__(16) float red[16 * 4 * NF];
  int tid = threadIdx.x;
  int row0 = blockIdx.x * 4;
  int wv = tid >> 6, lane = tid & 63, c4 = lane * 4;
  int rq = tid >> 8, c = tid & 255;
  AG[rq * 512 + c]       = obj[(row0 + rq) * NF + c];
  AG[rq * 512 + 256 + c] = part[((size_t)(row0 + rq) * 2 + 0) * NF + c]
                         + part[((size_t)(row0 + rq) * 2 + 1) * NF + c];
  __syncthreads();
  {
    int k0 = wv * 32;
    floatx4 acc[4] = {(floatx4)(0.f), (floatx4)(0.f), (floatx4)(0.f), (floatx4)(0.f)};
#pragma unroll
    for (int kb = 0; kb < 2; ++kb) {
      floatx4 w[16];
#pragma unroll
      for (int k = 0; k < 16; ++k)
        w[k] = *(const floatx4*)(ppw + (size_t)(k0 + kb * 16 + k) * NF + c4);
#pragma unroll
      for (int k = 0; k < 16; ++k) {
        int kk = k0 + kb * 16 + k;
#pragma unroll
        for (int r = 0; r < 4; ++r) acc[r] += AG[r * 512 + kk] * w[k];
      }
    }
#pragma unroll
    for (int r = 0; r < 4; ++r)
      *(floatx4*)(&red[(size_t)(wv * 4 + r) * NF + c4]) = acc[r];
  }
  __syncthreads();
  {
    float a = ppb[c];
#pragma unroll
    for (int ks = 0; ks < 16; ++ks) a += red[(size_t)(ks * 4 + rq) * NF + c];
    float o = fmaxf(a, 0.f);
    AG[rq * 512 + c] = o;
    obj_out[(row0 + rq) * NF + c] = o;
  }
  __syncthreads();
  {
    const float* W = (wv < 8) ? (rpw + 256 * NF) : (rpw + 512 * NF);
    int k0 = (wv & 7) * 32;
    floatx4 acc[4] = {(floatx4)(0.f), (floatx4)(0.f), (floatx4)(0.f), (floatx4)(0.f)};
#pragma unroll
    for (int kb = 0; kb < 2; ++kb) {
      floatx4 w[16];
#pragma unroll
      for (int k = 0; k < 16; ++k)
        w[k] = *(const floatx4*)(W + (size_t)(k0 + kb * 16 + k) * NF + c4);
#pragma unroll
      for (int k = 0; k < 16; ++k) {
        int kk = k0 + kb * 16 + k;
#pragma unroll
        for (int r = 0; r < 4; ++r) acc[r] += AG[r * 512 + kk] * w[k];
      }
    }
#pragma unroll
    for (int r = 0; r < 4; ++r)
      *(floatx4*)(&red[(size_t)(wv * 4 + r) * NF + c4]) = acc[r];
  }
  __syncthreads();
  {
    float q = rpb[c];
#pragma unroll
    for (int ks = 0; ks < 8; ++ks) q += red[(size_t)(ks * 4 + rq) * NF + c];
    float rr = 0.f;
#pragma unroll
    for (int ks = 8; ks < 16; ++ks) rr += red[(size_t)(ks * 4 + rq) * NF + c];
    Qo[(row0 + rq) * NF + c] = q;
    Ro[(row0 + rq) * NF + c] = rr;
  }
}

__global__ __launch_bounds__(1024) void aggupd_pred_kernel(
    const _Float16* __restrict__ P, const float* __restrict__ Q,
    const float* __restrict__ R, const float* __restrict__ obj,
    const float* __restrict__ ppw, const float* __restrict__ ppb,
    const float* __restrict__ w0, const float* __restrict__ b0,
    const float* __restrict__ w1, const float* __restrict__ b1,
    float* __restrict__ out)
{
  __shared__ float AG[4 * 512];
  __shared__ __align__(16) float red[16 * 4 * NF];
  int tid = threadIdx.x;
  int row0 = blockIdx.x * 4;
  int b = row0 >> 6;
  int wv = tid >> 6, lane = tid & 63, c4 = lane * 4;
  int rq = tid >> 8, c = tid & 255;
  {
    int rr = (tid >> 6) & 3;
    int jq = tid >> 8;
    float4 q4 = *(const float4*)(Q + (row0 + rr) * NF + c4);
    const _Float16* Pb = P + ((size_t)(row0 + rr) * NN + jq * 16) * NF + c4;
    const float* Rb = R + (size_t)(b * NN + jq * 16) * NF + c4;
    float4 s = make_float4(0.f, 0.f, 0.f, 0.f);
#pragma unroll
    for (int j = 0; j < 16; ++j) {
      half4 ph  = *(const half4*)(Pb + (size_t)j * NF);
      float4 rv = *(const float4*)(Rb + (size_t)j * NF);
      s.x += fmaxf((float)ph[0] + q4.x + rv.x, 0.f);
      s.y += fmaxf((float)ph[1] + q4.y + rv.y, 0.f);
      s.z += fmaxf((float)ph[2] + q4.z + rv.z, 0.f);
      s.w += fmaxf((float)ph[3] + q4.w + rv.w, 0.f);
    }
    *(float4*)(&red[(size_t)(jq * 4 + rr) * NF + c4]) = s;
    AG[rq * 512 + c] = obj[(row0 + rq) * NF + c];
  }
  __syncthreads();
  AG[rq * 512 + 256 + c] = red[(size_t)(0 * 4 + rq) * NF + c]
                         + red[(size_t)(1 * 4 + rq) * NF + c]
                         + red[(size_t)(2 * 4 + rq) * NF + c]
                         + red[(size_t)(3 * 4 + rq) * NF + c];
  __syncthreads();
  {
    int k0 = wv * 32;
    floatx4 acc[4] = {(floatx4)(0.f), (floatx4)(0.f), (floatx4)(0.f), (floatx4)(0.f)};
#pragma unroll
    for (int kb = 0; kb < 2; ++kb) {
      floatx4 w[16];
#pragma unroll
      for (int k = 0; k < 16; ++k)
        w[k] = *(const floatx4*)(ppw + (size_t)(k0 + kb * 16 + k) * NF + c4);
#pragma unroll
      for (int k = 0; k < 16; ++k) {
        int kk = k0 + kb * 16 + k;
#pragma unroll
        for (int r = 0; r < 4; ++r) acc[r] += AG[r * 512 + kk] * w[k];
      }
    }
#pragma unroll
    for (int r = 0; r < 4; ++r)
      *(floatx4*)(&red[(size_t)(wv * 4 + r) * NF + c4]) = acc[r];
  }
  __syncthreads();
  {
    float a = ppb[c];
#pragma unroll
    for (int ks = 0; ks < 16; ++ks) a += red[(size_t)(ks * 4 + rq) * NF + c];
    AG[rq * 512 + c] = fmaxf(a, 0.f);
  }
  __syncthreads();
  {
    floatx4 w[16];
#pragma unroll
    for (int k = 0; k < 16; ++k)
      w[k] = *(const floatx4*)(w0 + (size_t)(wv * 16 + k) * NF + c4);
    floatx4 acc[4] = {(floatx4)(0.f), (floatx4)(0.f), (floatx4)(0.f), (floatx4)(0.f)};
#pragma unroll
    for (int k = 0; k < 16; ++k) {
      int kk = wv * 16 + k;
#pragma unroll
      for (int r = 0; r < 4; ++r) acc[r] += AG[r * 512 + kk] * w[k];
    }
#pragma unroll
    for (int r = 0; r < 4; ++r)
      *(floatx4*)(&red[(size_t)(wv * 4 + r) * NF + c4]) = acc[r];
  }
  __syncthreads();
  {
    float a = b0[c];
#pragma unroll
    for (int ks = 0; ks < 16; ++ks) a += red[(size_t)(ks * 4 + rq) * NF + c];
    AG[rq * 512 + 256 + c] = fmaxf(a, 0.f);
  }
  __syncthreads();
  {
    int ks8 = tid >> 7, rr = (tid >> 5) & 3, g = tid & 31;
    float s = 0.f;
#pragma unroll 8
    for (int k = 0; k < 32; ++k)
      s += AG[rr * 512 + 256 + ks8 * 32 + k] * w1[(ks8 * 32 + k) * GG + g];
    red[tid] = s;
  }
  __syncthreads();
  if (tid < 4 * GG) {
    int rr = tid >> 5, g = tid & 31;
    float a = b1[g];
#pragma unroll
    for (int ks = 0; ks < 8; ++ks) a += red[ks * 128 + tid];
    out[(row0 + rr) * GG + g] = tanhf(a);
  }
}

extern "C" void kernel_launch(void* const* d_in, const int* in_sizes, int n_in,
                              void* d_out, int out_size, void* d_ws, size_t ws_size,
                              hipStream_t stream)
{
  const float* attrs     = (const float*)d_in[0];
  const float* states    = (const float*)d_in[1];
  const float* rel_attrs = (const float*)d_in[2];
  // d_in[3] = pstep (==2, structural)
  const float* enc_w0  = (const float*)d_in[4];
  const float* enc_b0  = (const float*)d_in[5];
  const float* enc_w1  = (const float*)d_in[6];
  const float* enc_b1  = (const float*)d_in[7];
  const float* rel_w0  = (const float*)d_in[8];
  const float* rel_b0  = (const float*)d_in[9];
  const float* rel_w1  = (const float*)d_in[10];
  const float* rel_b1  = (const float*)d_in[11];
  const float* rp_w    = (const float*)d_in[12];
  const float* rp_b    = (const float*)d_in[13];
  const float* pp_w    = (const float*)d_in[14];
  const float* pp_b    = (const float*)d_in[15];
  const float* pred_w0 = (const float*)d_in[16];
  const float* pred_b0 = (const float*)d_in[17];
  const float* pred_w1 = (const float*)d_in[18];
  const float* pred_b1 = (const float*)d_in[19];
  float* out = (float*)d_out;

  char* ws = (char*)d_ws;
  _Float16* P  = (_Float16*)ws;                             // 32 MB (fp16)
  float* obj0  = (float*)(ws + (size_t)NROWS_REL * NF * sizeof(_Float16));
  float* obj1  = obj0 + NROWS_OBJ * NF;
  float* Q0    = obj1 + NROWS_OBJ * NF;
  float* R0    = Q0 + NROWS_OBJ * NF;
  float* Q1    = R0 + NROWS_OBJ * NF;
  float* R1    = Q1 + NROWS_OBJ * NF;
  float* part1 = R1 + NROWS_OBJ * NF;                       // 2 MB
  _Float16* F0 = (_Float16*)(part1 + 2 * (size_t)NROWS_OBJ * NF);
  _Float16* F1 = F0 + F0_ELEMS;
  _Float16* F2 = F1 + F1_ELEMS;

  MegaArgs ma;
  ma.attrs = attrs; ma.states = states; ma.rel_attrs = rel_attrs;
  ma.enc_w0 = enc_w0; ma.enc_b0 = enc_b0; ma.enc_w1 = enc_w1; ma.enc_b1 = enc_b1;
  ma.rel_b0 = rel_b0; ma.rel_b1 = rel_b1;
  ma.rel_w0 = rel_w0; ma.rel_w1 = rel_w1;
  ma.rp_w = rp_w; ma.rp_b = rp_b; ma.pp_w = pp_w; ma.pp_b = pp_b;
  ma.pred_w0 = pred_w0; ma.pred_b0 = pred_b0;
  ma.pred_w1 = pred_w1; ma.pred_b1 = pred_b1;
  ma.F0 = F0; ma.F1 = F1; ma.F2 = F2; ma.P = P;
  ma.obj0 = obj0; ma.obj1 = obj1; ma.Q0 = Q0; ma.R0 = R0;
  ma.Q1 = Q1; ma.R1 = R1; ma.part1 = part1; ma.out = out;

  void* args[] = { &ma };
  hipError_t err = hipLaunchCooperativeKernel(
      reinterpret_cast<void*>(mega_kernel), dim3(1024), dim3(256),
      args, 0, stream);
  if (err != hipSuccess) {
    // ---- fallback: proven R21 4-dispatch path
    enc_qr_prep_kernel<<<NROWS_OBJ / 4, 1024, 0, stream>>>(
        attrs, states, enc_w0, enc_b0, enc_w1, enc_b1, rp_w, rp_b,
        rel_w0, rel_w1, F0, F1, F2, obj0, Q0, R0);
    rel_agg_store_mfma<<<NROWS_REL / ROWS, 256, 0, stream>>>(
        attrs, states, rel_attrs,
        F0, rel_b0, F1, rel_b1, F2,
        Q0, R0, P, part1);
    upd_qr_kernel<<<NROWS_OBJ / 4, 1024, 0, stream>>>(part1, obj0, pp_w, pp_b,
                                                      rp_w, rp_b, obj1, Q1, R1);
    aggupd_pred_kernel<<<NROWS_OBJ / 4, 1024, 0, stream>>>(P, Q1, R1, obj1,
                                                           pp_w, pp_b,
                                                           pred_w0, pred_b0,
                                                           pred_w1, pred_b1, out);
  }
}

// Round 9
// 189.760 us; speedup vs baseline: 7.5191x; 7.5191x over previous
//
#include <hip/hip_runtime.h>
#include <hip/hip_bf16.h>
#include <hip/hip_cooperative_groups.h>
#include <math.h>

namespace cg = cooperative_groups;

// Problem constants (fixed by reference setup_inputs)
#define BB 16
#define NN 64
#define ATTR 4
#define STATE 16
#define RELD 9
#define GG 32
#define NF 256
#define NROWS_OBJ (BB*NN)        // 1024
#define NROWS_REL (BB*NN*NN)     // 65536

typedef _Float16 half8 __attribute__((ext_vector_type(8)));
typedef _Float16 half4 __attribute__((ext_vector_type(4)));
typedef float  floatx4 __attribute__((ext_vector_type(4)));

// fp16 split: x ~= h + l, |x-(h+l)| ~ 2^-22 |x| (A-operand use only)
__device__ __forceinline__ void split2h(float x, _Float16& h, _Float16& l) {
  h = (_Float16)x;
  l = (_Float16)(x - (float)h);
}

#define F0_ELEMS (2 * 16 * 64 * 8)   // 16384
#define F1_ELEMS (8 * 16 * 64 * 8)   // 65536
#define F_TOTAL  (F0_ELEMS + 2 * F1_ELEMS)

#define ROWS 32
#define NRT 2
#define HSTR 264
#define XSTR 72

// ---------------------------------------------------------------------------
// Frozen rel tile body (R15 form, measured 58-62 us standalone).
// ---------------------------------------------------------------------------
#define ZERO_ACC() do { \
  _Pragma("unroll") for (int rt = 0; rt < NRT; ++rt) \
  _Pragma("unroll") for (int ct = 0; ct < 4; ++ct) acc[rt][ct] = (floatx4)(0.f); } while (0)

#define STAGE(Sn, AH, AL, ASTR, BF) do { \
  half8 ah[2][NRT], al[2][NRT], bf[2][4]; \
  _Pragma("unroll") for (int ct = 0; ct < 4; ++ct) \
    bf[0][ct] = *(const half8*)((BF) + (size_t)((wave * 4 + ct) * 64 + lane) * 8); \
  _Pragma("unroll") for (int rt = 0; rt < NRT; ++rt) { \
    ah[0][rt] = *(const half8*)(&(AH)[(rt * 16 + l16) * (ASTR) + quad * 8]); \
    al[0][rt] = *(const half8*)(&(AL)[(rt * 16 + l16) * (ASTR) + quad * 8]); } \
  _Pragma("unroll") \
  for (int s = 0; s < (Sn); ++s) { \
    int cur = s & 1, nxt = cur ^ 1; \
    if (s + 1 < (Sn)) { \
      _Pragma("unroll") for (int ct = 0; ct < 4; ++ct) \
        bf[nxt][ct] = *(const half8*)((BF) + (size_t)(((s + 1) * 16 + wave * 4 + ct) * 64 + lane) * 8); \
      _Pragma("unroll") for (int rt = 0; rt < NRT; ++rt) { \
        ah[nxt][rt] = *(const half8*)(&(AH)[(rt * 16 + l16) * (ASTR) + (s + 1) * 32 + quad * 8]); \
        al[nxt][rt] = *(const half8*)(&(AL)[(rt * 16 + l16) * (ASTR) + (s + 1) * 32 + quad * 8]); } } \
    _Pragma("unroll") for (int rt = 0; rt < NRT; ++rt) \
    _Pragma("unroll") for (int ct = 0; ct < 4; ++ct) { \
      acc[rt][ct] = __builtin_amdgcn_mfma_f32_16x16x32_f16(ah[cur][rt], bf[cur][ct], acc[rt][ct], 0, 0, 0); \
      acc[rt][ct] = __builtin_amdgcn_mfma_f32_16x16x32_f16(al[cur][rt], bf[cur][ct], acc[rt][ct], 0, 0, 0); } \
  } } while (0)

__device__ __forceinline__ void rel_tile(
    _Float16* S, int tid, int row0,
    const float* __restrict__ attrs, const float* __restrict__ states,
    const float* __restrict__ rel_attrs,
    const _Float16* __restrict__ F0, const float* __restrict__ b0,
    const _Float16* __restrict__ F1, const float* __restrict__ b1,
    const _Float16* __restrict__ F2,
    const float* __restrict__ Q, const float* __restrict__ R,
    _Float16* __restrict__ P, float* __restrict__ part)
{
  _Float16* Hh = S;
  _Float16* Hl = S + ROWS * HSTR;
  _Float16* Xh = Hh;   // X aliased onto H (dead after stage 1)
  _Float16* Xl = Hl;

  int wave = tid >> 6;
  int lane = tid & 63;
  int quad = lane >> 4;
  int l16  = lane & 15;

  for (int idx = tid; idx < ROWS * 64; idx += 256) {
    int r = idx >> 6, k = idx & 63;
    int grow = row0 + r;
    int j = grow & 63, i = (grow >> 6) & 63, b = grow >> 12;
    float v = 0.f;
    if (k < RELD)                     v = rel_attrs[(size_t)grow * RELD + k];
    else if (k < RELD + STATE)        v = states[(b * NN + i) * STATE + (k - RELD)]
                                        - states[(b * NN + j) * STATE + (k - RELD)];
    else if (k < RELD + STATE + ATTR) v = attrs[(b * NN + i) * ATTR + (k - RELD - STATE)];
    else if (k < 33)                  v = attrs[(b * NN + j) * ATTR + (k - RELD - STATE - ATTR)];
    _Float16 h, l; split2h(v, h, l);
    Xh[r * XSTR + k] = h;
    Xl[r * XSTR + k] = l;
  }
  __syncthreads();

  floatx4 acc[NRT][4];

  // ---- stage 1: H = ReLU(X @ W0 + b0), K=64 (padded)
  ZERO_ACC();
  STAGE(2, Xh, Xl, XSTR, F0);
  __syncthreads();  // X reads done before H overwrites the aliased region
#pragma unroll
  for (int ct = 0; ct < 4; ++ct) {
    int col = wave * 64 + ct * 16 + l16;
    float bias = b0[col];
#pragma unroll
    for (int rt = 0; rt < NRT; ++rt)
#pragma unroll
      for (int r = 0; r < 4; ++r) {
        int row = rt * 16 + quad * 4 + r;
        float h = fmaxf(acc[rt][ct][r] + bias, 0.f);
        split2h(h, Hh[row * HSTR + col], Hl[row * HSTR + col]);
      }
  }
  __syncthreads();

  // ---- stage 2: E = ReLU(H @ W1 + b1), K=256
  ZERO_ACC();
  STAGE(8, Hh, Hl, HSTR, F1);
  __syncthreads();
#pragma unroll
  for (int ct = 0; ct < 4; ++ct) {
    int col = wave * 64 + ct * 16 + l16;
    float bias = b1[col];
#pragma unroll
    for (int rt = 0; rt < NRT; ++rt)
#pragma unroll
      for (int r = 0; r < 4; ++r) {
        int row = rt * 16 + quad * 4 + r;
        float e = fmaxf(acc[rt][ct][r] + bias, 0.f);
        split2h(e, Hh[row * HSTR + col], Hl[row * HSTR + col]);
      }
  }
  __syncthreads();

  // ---- stage 3: P-tile in registers (K=256)
  ZERO_ACC();
  STAGE(8, Hh, Hl, HSTR, F2);

  // ---- store P fp16 (pstep 2 reads it in the sweep)
#pragma unroll
  for (int ct = 0; ct < 4; ++ct) {
    int col = wave * 64 + ct * 16 + l16;
#pragma unroll
    for (int rt = 0; rt < NRT; ++rt)
#pragma unroll
      for (int r = 0; r < 4; ++r) {
        int row = rt * 16 + quad * 4 + r;
        P[(size_t)(row0 + row) * NF + col] = (_Float16)acc[rt][ct][r];
      }
  }
  __syncthreads();                       // all E reads done — LDS reusable

  // ---- fused pstep-1 aggregation epilogue (exact fp32 acc)
  {
    float* Rs = (float*)S;               // 32 x 256 fp32 R-tile (32KB)
    int bi    = row0 >> 6;
    int jbase = row0 & 63;               // 0 or 32
    int b     = row0 >> 12;
    for (int idx = tid; idx < ROWS * NF; idx += 256) {
      int rr = idx >> 8, cc = idx & 255;
      Rs[idx] = R[(size_t)(b * NN + jbase + rr) * NF + cc];
    }
    __syncthreads();
#pragma unroll
    for (int ct = 0; ct < 4; ++ct) {
      int col = wave * 64 + ct * 16 + l16;
      float q = Q[bi * NF + col];
      float s = 0.f;
#pragma unroll
      for (int rt = 0; rt < NRT; ++rt)
#pragma unroll
        for (int r = 0; r < 4; ++r) {
          int row = rt * 16 + quad * 4 + r;
          s += fmaxf(acc[rt][ct][r] + q + Rs[row * NF + col], 0.f);
        }
      s += __shfl_xor(s, 16, 64);        // quad butterfly: rows 0..31 summed
      s += __shfl_xor(s, 32, 64);
      if (quad == 0)
        part[((size_t)bi * 2 + (jbase >> 5)) * NF + col] = s;
    }
  }
}
#undef ZERO_ACC
#undef STAGE

// ---------------------------------------------------------------------------
// R24: mega-kernel with launch_bounds(256, 2).  R23's (256,4) empirically
// caps VGPR at 64 (rule: cap ~= 512/(2*minwaves); R16's (256,5)->48 fits) —
// the 10-phase body spilled ~460 MB of scratch -> 1350 us.  (256,2) raises
// the cap to 128; at V<=128 occupancy is still 4 waves/SIMD x 4 blocks/CU
// (LDS 33792*4 <= 160K), so the 1024-block cooperative launch remains
// co-resident.  Host-side occupancy guard (>=4 blocks/CU) + launch-error
// check fall back to the proven R21 4-dispatch path (186.8 us).
// Mega numerics already hardware-verified in R23 (passed, absmax 0.015625).
// ---------------------------------------------------------------------------
struct MegaArgs {
  const float *attrs, *states, *rel_attrs;
  const float *enc_w0, *enc_b0, *enc_w1, *enc_b1;
  const float *rel_b0, *rel_b1;
  const float *rel_w0, *rel_w1;
  const float *rp_w, *rp_b, *pp_w, *pp_b;
  const float *pred_w0, *pred_b0, *pred_w1, *pred_b1;
  _Float16 *F0, *F1, *F2, *P;
  float *obj0, *obj1, *Q0, *R0, *Q1, *R1, *part1, *out;
};

__global__ __launch_bounds__(256, 2) void mega_kernel(MegaArgs a)
{
  cg::grid_group grid = cg::this_grid();
  __shared__ __align__(16) _Float16 S[2 * ROWS * HSTR];   // 33792 B
  int tid = threadIdx.x, bid = blockIdx.x;

  // ---- A: F-prep (single pass; 262144 threads >= F_TOTAL)
  {
    int idx = bid * 256 + tid;
    if (idx < F0_ELEMS) {
      int j = idx & 7, lane = (idx >> 3) & 63, g = (idx >> 9) & 15, s = idx >> 13;
      int k = s * 32 + (lane >> 4) * 8 + j, n = g * 16 + (lane & 15);
      float v = (k < 33) ? a.rel_w0[k * NF + n] : 0.f;
      a.F0[idx] = (_Float16)v;
    } else if (idx < F0_ELEMS + F1_ELEMS) {
      int t = idx - F0_ELEMS;
      int j = t & 7, lane = (t >> 3) & 63, g = (t >> 9) & 15, s = t >> 13;
      int k = s * 32 + (lane >> 4) * 8 + j, n = g * 16 + (lane & 15);
      a.F1[t] = (_Float16)a.rel_w1[k * NF + n];
    } else if (idx < F_TOTAL) {
      int t = idx - (F0_ELEMS + F1_ELEMS);
      int j = t & 7, lane = (t >> 3) & 63, g = (t >> 9) & 15, s = t >> 13;
      int k = s * 32 + (lane >> 4) * 8 + j, n = g * 16 + (lane & 15);
      a.F2[t] = (_Float16)a.rp_w[k * NF + n];
    }
  }

  // ---- B: enc H (redundant 16-row tile in LDS, K=20) + obj0 16x16 tile
  {
    float* Hs = (float*)S;            // 16 x 260 fp32 = 16.6 KB
    int mt = bid >> 4, nt = bid & 15;
    int row0 = mt * 16;
    for (int t = 0; t < 16; ++t) {
      int idx = t * 256 + tid;
      int r = idx >> 8, cc = idx & 255;
      int m = row0 + r;
      float v = a.enc_b0[cc];
#pragma unroll
      for (int k = 0; k < 20; ++k) {
        float x = (k < ATTR) ? a.attrs[m * ATTR + k] : a.states[m * STATE + (k - ATTR)];
        v += x * a.enc_w0[k * NF + cc];
      }
      Hs[r * 260 + cc] = fmaxf(v, 0.f);
    }
    __syncthreads();
    int r = tid >> 4, c = tid & 15;
    int col = nt * 16 + c;
    float acc = a.enc_b1[col];
#pragma unroll 8
    for (int k = 0; k < 256; ++k)
      acc += Hs[r * 260 + k] * a.enc_w1[(size_t)k * NF + col];
    a.obj0[(size_t)(row0 + r) * NF + col] = fmaxf(acc, 0.f);
    __syncthreads();                    // Hs reads done before rel reuses S
  }
  grid.sync();

  // ---- C: Q0 | R0 (2048 tiles of 16x16, 2 per block)
#pragma unroll
  for (int t = 0; t < 2; ++t) {
    int tt = bid + t * 1024;
    int mt = tt >> 5, ntc = tt & 31;
    int row = mt * 16 + (tid >> 4);
    int c512 = ntc * 16 + (tid & 15);
    const float* Arow = a.obj0 + (size_t)row * NF;
    if (c512 < 256) {
      float acc = a.rp_b[c512];
      const float* W = a.rp_w + 256 * NF + c512;
#pragma unroll 8
      for (int k = 0; k < 256; ++k) acc += Arow[k] * W[(size_t)k * NF];
      a.Q0[(size_t)row * NF + c512] = acc;
    } else {
      float acc = 0.f;
      const float* W = a.rp_w + 512 * NF + (c512 - 256);
#pragma unroll 8
      for (int k = 0; k < 256; ++k) acc += Arow[k] * W[(size_t)k * NF];
      a.R0[(size_t)row * NF + (c512 - 256)] = acc;
    }
  }
  grid.sync();

  // ---- D: rel chain, 2 row-tiles per block (frozen body)
  for (int it = 0; it < 2; ++it) {
    rel_tile(S, tid, (it * 1024 + bid) * ROWS,
             a.attrs, a.states, a.rel_attrs, a.F0, a.rel_b0, a.F1, a.rel_b1,
             a.F2, a.Q0, a.R0, a.P, a.part1);
    __syncthreads();
  }
  grid.sync();

  // ---- E: upd1 -> obj1   (K = 512: [obj0 | part-pair-sum] @ pp_w)
  {
    int mt = bid >> 4, nt = bid & 15;
    int row = mt * 16 + (tid >> 4);
    int col = nt * 16 + (tid & 15);
    float acc = a.pp_b[col];
    const float* Ao = a.obj0 + (size_t)row * NF;
    const float* W1 = a.pp_w + col;
#pragma unroll 8
    for (int k = 0; k < 256; ++k) acc += Ao[k] * W1[(size_t)k * NF];
    const float* G0 = a.part1 + (size_t)row * 2 * NF;
    const float* W2 = a.pp_w + (size_t)256 * NF + col;
#pragma unroll 8
    for (int k = 0; k < 256; ++k) acc += (G0[k] + G0[NF + k]) * W2[(size_t)k * NF];
    a.obj1[(size_t)row * NF + col] = fmaxf(acc, 0.f);
  }
  grid.sync();

  // ---- F: Q1 | R1
#pragma unroll
  for (int t = 0; t < 2; ++t) {
    int tt = bid + t * 1024;
    int mt = tt >> 5, ntc = tt & 31;
    int row = mt * 16 + (tid >> 4);
    int c512 = ntc * 16 + (tid & 15);
    const float* Arow = a.obj1 + (size_t)row * NF;
    if (c512 < 256) {
      float acc = a.rp_b[c512];
      const float* W = a.rp_w + 256 * NF + c512;
#pragma unroll 8
      for (int k = 0; k < 256; ++k) acc += Arow[k] * W[(size_t)k * NF];
      a.Q1[(size_t)row * NF + c512] = acc;
    } else {
      float acc = 0.f;
      const float* W = a.rp_w + 512 * NF + (c512 - 256);
#pragma unroll 8
      for (int k = 0; k < 256; ++k) acc += Arow[k] * W[(size_t)k * NF];
      a.R1[(size_t)row * NF + (c512 - 256)] = acc;
    }
  }
  grid.sync();

  // ---- G: pstep-2 sweep -> G2 (overlays part1; part1 consumed in E)
  {
    int mt = bid >> 4, nt = bid & 15;
    int i = mt * 16 + (tid >> 4);
    int col = nt * 16 + (tid & 15);
    int b = i >> 6;
    float q = a.Q1[(size_t)i * NF + col];
    const _Float16* Pb = a.P + (size_t)i * NN * NF + col;
    const float* Rb = a.R1 + (size_t)(b * NN) * NF + col;
    float s = 0.f;
#pragma unroll 8
    for (int j = 0; j < NN; ++j)
      s += fmaxf((float)Pb[(size_t)j * NF] + q + Rb[(size_t)j * NF], 0.f);
    a.part1[(size_t)i * NF + col] = s;
  }
  grid.sync();

  // ---- H: upd2 -> obj2 (overlays obj0; obj0 consumed in E)
  {
    int mt = bid >> 4, nt = bid & 15;
    int row = mt * 16 + (tid >> 4);
    int col = nt * 16 + (tid & 15);
    float acc = a.pp_b[col];
    const float* Ao = a.obj1 + (size_t)row * NF;
    const float* W1 = a.pp_w + col;
#pragma unroll 8
    for (int k = 0; k < 256; ++k) acc += Ao[k] * W1[(size_t)k * NF];
    const float* G2 = a.part1 + (size_t)row * NF;
    const float* W2 = a.pp_w + (size_t)256 * NF + col;
#pragma unroll 8
    for (int k = 0; k < 256; ++k) acc += G2[k] * W2[(size_t)k * NF];
    a.obj0[(size_t)row * NF + col] = fmaxf(acc, 0.f);
  }
  grid.sync();

  // ---- I: pred1 -> T (overlays Q0; Q0 consumed in D)
  {
    int mt = bid >> 4, nt = bid & 15;
    int row = mt * 16 + (tid >> 4);
    int col = nt * 16 + (tid & 15);
    float acc = a.pred_b0[col];
    const float* Ao = a.obj0 + (size_t)row * NF;
    const float* W = a.pred_w0 + col;
#pragma unroll 8
    for (int k = 0; k < 256; ++k) acc += Ao[k] * W[(size_t)k * NF];
    a.Q0[(size_t)row * NF + col] = fmaxf(acc, 0.f);
  }
  grid.sync();

  // ---- J: pred2 -> out (128 tiles; others idle)
  if (bid < 128) {
    int mt = bid >> 1, nt = bid & 1;
    int row = mt * 16 + (tid >> 4);
    int col = nt * 16 + (tid & 15);
    float acc = a.pred_b1[col];
    const float* T = a.Q0 + (size_t)row * NF;
#pragma unroll 8
    for (int k = 0; k < 256; ++k) acc += T[k] * a.pred_w1[k * GG + col];
    a.out[(size_t)row * GG + col] = tanhf(acc);
  }
}

// ===========================================================================
// FALLBACK PATH — exact R21 kernels (proven 186.8 us).
// ===========================================================================
__global__ __launch_bounds__(256, 4) void rel_agg_store_mfma(
    const float* __restrict__ attrs, const float* __restrict__ states,
    const float* __restrict__ rel_attrs,
    const _Float16* __restrict__ F0, const float* __restrict__ b0,
    const _Float16* __restrict__ F1, const float* __restrict__ b1,
    const _Float16* __restrict__ F2,
    const float* __restrict__ Q, const float* __restrict__ R,
    _Float16* __restrict__ P, float* __restrict__ part)
{
  __shared__ __align__(16) _Float16 S[2 * ROWS * HSTR];
  rel_tile(S, threadIdx.x, blockIdx.x * ROWS,
           attrs, states, rel_attrs, F0, b0, F1, b1, F2, Q, R, P, part);
}

__global__ __launch_bounds__(1024) void enc_qr_prep_kernel(
    const float* __restrict__ attrs, const float* __restrict__ states,
    const float* __restrict__ w0, const float* __restrict__ b0,
    const float* __restrict__ w1, const float* __restrict__ b1,
    const float* __restrict__ rpw, const float* __restrict__ rpb,
    const float* __restrict__ rel_w0, const float* __restrict__ rel_w1,
    _Float16* __restrict__ F0, _Float16* __restrict__ F1,
    _Float16* __restrict__ F2,
    float* __restrict__ obj, float* __restrict__ Q, float* __restrict__ R)
{
  int tid = threadIdx.x;
  for (int idx = blockIdx.x * 1024 + tid; idx < F_TOTAL; idx += 256 * 1024) {
    if (idx < F0_ELEMS) {
      int j = idx & 7, lane = (idx >> 3) & 63, g = (idx >> 9) & 15, s = idx >> 13;
      int k = s * 32 + (lane >> 4) * 8 + j, n = g * 16 + (lane & 15);
      float v = (k < 33) ? rel_w0[k * NF + n] : 0.f;
      F0[idx] = (_Float16)v;
    } else if (idx < F0_ELEMS + F1_ELEMS) {
      int t = idx - F0_ELEMS;
      int j = t & 7, lane = (t >> 3) & 63, g = (t >> 9) & 15, s = t >> 13;
      int k = s * 32 + (lane >> 4) * 8 + j, n = g * 16 + (lane & 15);
      F1[t] = (_Float16)rel_w1[k * NF + n];
    } else {
      int t = idx - (F0_ELEMS + F1_ELEMS);
      int j = t & 7, lane = (t >> 3) & 63, g = (t >> 9) & 15, s = t >> 13;
      int k = s * 32 + (lane >> 4) * 8 + j, n = g * 16 + (lane & 15);
      F2[t] = (_Float16)rpw[k * NF + n];
    }
  }
  __shared__ float X[4 * 20];
  __shared__ float HO[4 * NF];
  __shared__ __align__(16) float red[16 * 4 * NF];
  int row0 = blockIdx.x * 4;
  if (tid < 80) {
    int r = tid / 20, k = tid % 20;
    int m = row0 + r;
    X[tid] = (k < ATTR) ? attrs[m * ATTR + k] : states[m * STATE + (k - ATTR)];
  }
  __syncthreads();
  int wv = tid >> 6, lane = tid & 63, c4 = lane * 4;
  int rq = tid >> 8, c = tid & 255;
  {
    float a = b0[c];
#pragma unroll
    for (int k = 0; k < 20; ++k) a += X[rq * 20 + k] * w0[k * NF + c];
    HO[rq * NF + c] = fmaxf(a, 0.f);
  }
  __syncthreads();
  {
    floatx4 w[16];
#pragma unroll
    for (int k = 0; k < 16; ++k)
      w[k] = *(const floatx4*)(w1 + (size_t)(wv * 16 + k) * NF + c4);
    floatx4 acc[4] = {(floatx4)(0.f), (floatx4)(0.f), (floatx4)(0.f), (floatx4)(0.f)};
#pragma unroll
    for (int k = 0; k < 16; ++k) {
      int kk = wv * 16 + k;
#pragma unroll
      for (int r = 0; r < 4; ++r) acc[r] += HO[r * NF + kk] * w[k];
    }
#pragma unroll
    for (int r = 0; r < 4; ++r)
      *(floatx4*)(&red[(size_t)(wv * 4 + r) * NF + c4]) = acc[r];
  }
  __syncthreads();
  {
    float a = b1[c];
#pragma unroll
    for (int ks = 0; ks < 16; ++ks) a += red[(size_t)(ks * 4 + rq) * NF + c];
    a = fmaxf(a, 0.f);
    HO[rq * NF + c] = a;
    obj[(row0 + rq) * NF + c] = a;
  }
  __syncthreads();
  {
    const float* W = (wv < 8) ? (rpw + 256 * NF) : (rpw + 512 * NF);
    int k0 = (wv & 7) * 32;
    floatx4 acc[4] = {(floatx4)(0.f), (floatx4)(0.f), (floatx4)(0.f), (floatx4)(0.f)};
#pragma unroll
    for (int kb = 0; kb < 2; ++kb) {
      floatx4 w[16];
#pragma unroll
      for (int k = 0; k < 16; ++k)
        w[k] = *(const floatx4*)(W + (size_t)(k0 + kb * 16 + k) * NF + c4);
#pragma unroll
      for (int k = 0; k < 16; ++k) {
        int kk = k0 + kb * 16 + k;
#pragma unroll
        for (int r = 0; r < 4; ++r) acc[r] += HO[r * NF + kk] * w[k];
      }
    }
#pragma unroll
    for (int r = 0; r < 4; ++r)
      *(floatx4*)(&red[(size_t)(wv * 4 + r) * NF + c4]) = acc[r];
  }
  __syncthreads();
  {
    float q = rpb[c];
#pragma unroll
    for (int ks = 0; ks < 8; ++ks) q += red[(size_t)(ks * 4 + rq) * NF + c];
    float rr = 0.f;
#pragma unroll
    for (int ks = 8; ks < 16; ++ks) rr += red[(size_t)(ks * 4 + rq) * NF + c];
    Q[(row0 + rq) * NF + c] = q;
    R[(row0 + rq) * NF + c] = rr;
  }
}

__global__ __launch_bounds__(1024) void upd_qr_kernel(
    const float* __restrict__ part, const float* __restrict__ obj,
    const float* __restrict__ ppw, const float* __restrict__ ppb,
    const float* __restrict__ rpw, const float* __restrict__ rpb,
    float* __restrict__ obj_out, float* __restrict__ Qo, float* __restrict__ Ro)
{
  __shared__ float AG[4 * 512];
  __shared__ __align__(16) float red[16 * 4 * NF];
  int tid = threadIdx.x;
  int row0 = blockIdx.x * 4;
  int wv = tid >> 6, lane = tid & 63, c4 = lane * 4;
  int rq = tid >> 8, c = tid & 255;
  AG[rq * 512 + c]       = obj[(row0 + rq) * NF + c];
  AG[rq * 512 + 256 + c] = part[((size_t)(row0 + rq) * 2 + 0) * NF + c]
                         + part[((size_t)(row0 + rq) * 2 + 1) * NF + c];
  __syncthreads();
  {
    int k0 = wv * 32;
    floatx4 acc[4] = {(floatx4)(0.f), (floatx4)(0.f), (floatx4)(0.f), (floatx4)(0.f)};
#pragma unroll
    for (int kb = 0; kb < 2; ++kb) {
      floatx4 w[16];
#pragma unroll
      for (int k = 0; k < 16; ++k)
        w[k] = *(const floatx4*)(ppw + (size_t)(k0 + kb * 16 + k) * NF + c4);
#pragma unroll
      for (int k = 0; k < 16; ++k) {
        int kk = k0 + kb * 16 + k;
#pragma unroll
        for (int r = 0; r < 4; ++r) acc[r] += AG[r * 512 + kk] * w[k];
      }
    }
#pragma unroll
    for (int r = 0; r < 4; ++r)
      *(floatx4*)(&red[(size_t)(wv * 4 + r) * NF + c4]) = acc[r];
  }
  __syncthreads();
  {
    float a = ppb[c];
#pragma unroll
    for (int ks = 0; ks < 16; ++ks) a += red[(size_t)(ks * 4 + rq) * NF + c];
    float o = fmaxf(a, 0.f);
    AG[rq * 512 + c] = o;
    obj_out[(row0 + rq) * NF + c] = o;
  }
  __syncthreads();
  {
    const float* W = (wv < 8) ? (rpw + 256 * NF) : (rpw + 512 * NF);
    int k0 = (wv & 7) * 32;
    floatx4 acc[4] = {(floatx4)(0.f), (floatx4)(0.f), (floatx4)(0.f), (floatx4)(0.f)};
#pragma unroll
    for (int kb = 0; kb < 2; ++kb) {
      floatx4 w[16];
#pragma unroll
      for (int k = 0; k < 16; ++k)
        w[k] = *(const floatx4*)(W + (size_t)(k0 + kb * 16 + k) * NF + c4);
#pragma unroll
      for (int k = 0; k < 16; ++k) {
        int kk = k0 + kb * 16 + k;
#pragma unroll
        for (int r = 0; r < 4; ++r) acc[r] += AG[r * 512 + kk] * w[k];
      }
    }
#pragma unroll
    for (int r = 0; r < 4; ++r)
      *(floatx4*)(&red[(size_t)(wv * 4 + r) * NF + c4]) = acc[r];
  }
  __syncthreads();
  {
    float q = rpb[c];
#pragma unroll
    for (int ks = 0; ks < 8; ++ks) q += red[(size_t)(ks * 4 + rq) * NF + c];
    float rr = 0.f;
#pragma unroll
    for (int ks = 8; ks < 16; ++ks) rr += red[(size_t)(ks * 4 + rq) * NF + c];
    Qo[(row0 + rq) * NF + c] = q;
    Ro[(row0 + rq) * NF + c] = rr;
  }
}

__global__ __launch_bounds__(1024) void aggupd_pred_kernel(
    const _Float16* __restrict__ P, const float* __restrict__ Q,
    const float* __restrict__ R, const float* __restrict__ obj,
    const float* __restrict__ ppw, const float* __restrict__ ppb,
    const float* __restrict__ w0, const float* __restrict__ b0,
    const float* __restrict__ w1, const float* __restrict__ b1,
    float* __restrict__ out)
{
  __shared__ float AG[4 * 512];
  __shared__ __align__(16) float red[16 * 4 * NF];
  int tid = threadIdx.x;
  int row0 = blockIdx.x * 4;
  int b = row0 >> 6;
  int wv = tid >> 6, lane = tid & 63, c4 = lane * 4;
  int rq = tid >> 8, c = tid & 255;
  {
    int rr = (tid >> 6) & 3;
    int jq = tid >> 8;
    float4 q4 = *(const float4*)(Q + (row0 + rr) * NF + c4);
    const _Float16* Pb = P + ((size_t)(row0 + rr) * NN + jq * 16) * NF + c4;
    const float* Rb = R + (size_t)(b * NN + jq * 16) * NF + c4;
    float4 s = make_float4(0.f, 0.f, 0.f, 0.f);
#pragma unroll
    for (int j = 0; j < 16; ++j) {
      half4 ph  = *(const half4*)(Pb + (size_t)j * NF);
      float4 rv = *(const float4*)(Rb + (size_t)j * NF);
      s.x += fmaxf((float)ph[0] + q4.x + rv.x, 0.f);
      s.y += fmaxf((float)ph[1] + q4.y + rv.y, 0.f);
      s.z += fmaxf((float)ph[2] + q4.z + rv.z, 0.f);
      s.w += fmaxf((float)ph[3] + q4.w + rv.w, 0.f);
    }
    *(float4*)(&red[(size_t)(jq * 4 + rr) * NF + c4]) = s;
    AG[rq * 512 + c] = obj[(row0 + rq) * NF + c];
  }
  __syncthreads();
  AG[rq * 512 + 256 + c] = red[(size_t)(0 * 4 + rq) * NF + c]
                         + red[(size_t)(1 * 4 + rq) * NF + c]
                         + red[(size_t)(2 * 4 + rq) * NF + c]
                         + red[(size_t)(3 * 4 + rq) * NF + c];
  __syncthreads();
  {
    int k0 = wv * 32;
    floatx4 acc[4] = {(floatx4)(0.f), (floatx4)(0.f), (floatx4)(0.f), (floatx4)(0.f)};
#pragma unroll
    for (int kb = 0; kb < 2; ++kb) {
      floatx4 w[16];
#pragma unroll
      for (int k = 0; k < 16; ++k)
        w[k] = *(const floatx4*)(ppw + (size_t)(k0 + kb * 16 + k) * NF + c4);
#pragma unroll
      for (int k = 0; k < 16; ++k) {
        int kk = k0 + kb * 16 + k;
#pragma unroll
        for (int r = 0; r < 4; ++r) acc[r] += AG[r * 512 + kk] * w[k];
      }
    }
#pragma unroll
    for (int r = 0; r < 4; ++r)
      *(floatx4*)(&red[(size_t)(wv * 4 + r) * NF + c4]) = acc[r];
  }
  __syncthreads();
  {
    float a = ppb[c];
#pragma unroll
    for (int ks = 0; ks < 16; ++ks) a += red[(size_t)(ks * 4 + rq) * NF + c];
    AG[rq * 512 + c] = fmaxf(a, 0.f);
  }
  __syncthreads();
  {
    floatx4 w[16];
#pragma unroll
    for (int k = 0; k < 16; ++k)
      w[k] = *(const floatx4*)(w0 + (size_t)(wv * 16 + k) * NF + c4);
    floatx4 acc[4] = {(floatx4)(0.f), (floatx4)(0.f), (floatx4)(0.f), (floatx4)(0.f)};
#pragma unroll
    for (int k = 0; k < 16; ++k) {
      int kk = wv * 16 + k;
#pragma unroll
      for (int r = 0; r < 4; ++r) acc[r] += AG[r * 512 + kk] * w[k];
    }
#pragma unroll
    for (int r = 0; r < 4; ++r)
      *(floatx4*)(&red[(size_t)(wv * 4 + r) * NF + c4]) = acc[r];
  }
  __syncthreads();
  {
    float a = b0[c];
#pragma unroll
    for (int ks = 0; ks < 16; ++ks) a += red[(size_t)(ks * 4 + rq) * NF + c];
    AG[rq * 512 + 256 + c] = fmaxf(a, 0.f);
  }
  __syncthreads();
  {
    int ks8 = tid >> 7, rr = (tid >> 5) & 3, g = tid & 31;
    float s = 0.f;
#pragma unroll 8
    for (int k = 0; k < 32; ++k)
      s += AG[rr * 512 + 256 + ks8 * 32 + k] * w1[(ks8 * 32 + k) * GG + g];
    red[tid] = s;
  }
  __syncthreads();
  if (tid < 4 * GG) {
    int rr = tid >> 5, g = tid & 31;
    float a = b1[g];
#pragma unroll
    for (int ks = 0; ks < 8; ++ks) a += red[ks * 128 + tid];
    out[(row0 + rr) * GG + g] = tanhf(a);
  }
}

extern "C" void kernel_launch(void* const* d_in, const int* in_sizes, int n_in,
                              void* d_out, int out_size, void* d_ws, size_t ws_size,
                              hipStream_t stream)
{
  const float* attrs     = (const float*)d_in[0];
  const float* states    = (const float*)d_in[1];
  const float* rel_attrs = (const float*)d_in[2];
  // d_in[3] = pstep (==2, structural)
  const float* enc_w0  = (const float*)d_in[4];
  const float* enc_b0  = (const float*)d_in[5];
  const float* enc_w1  = (const float*)d_in[6];
  const float* enc_b1  = (const float*)d_in[7];
  const float* rel_w0  = (const float*)d_in[8];
  const float* rel_b0  = (const float*)d_in[9];
  const float* rel_w1  = (const float*)d_in[10];
  const float* rel_b1  = (const float*)d_in[11];
  const float* rp_w    = (const float*)d_in[12];
  const float* rp_b    = (const float*)d_in[13];
  const float* pp_w    = (const float*)d_in[14];
  const float* pp_b    = (const float*)d_in[15];
  const float* pred_w0 = (const float*)d_in[16];
  const float* pred_b0 = (const float*)d_in[17];
  const float* pred_w1 = (const float*)d_in[18];
  const float* pred_b1 = (const float*)d_in[19];
  float* out = (float*)d_out;

  char* ws = (char*)d_ws;
  _Float16* P  = (_Float16*)ws;                             // 32 MB (fp16)
  float* obj0  = (float*)(ws + (size_t)NROWS_REL * NF * sizeof(_Float16));
  float* obj1  = obj0 + NROWS_OBJ * NF;
  float* Q0    = obj1 + NROWS_OBJ * NF;
  float* R0    = Q0 + NROWS_OBJ * NF;
  float* Q1    = R0 + NROWS_OBJ * NF;
  float* R1    = Q1 + NROWS_OBJ * NF;
  float* part1 = R1 + NROWS_OBJ * NF;                       // 2 MB
  _Float16* F0 = (_Float16*)(part1 + 2 * (size_t)NROWS_OBJ * NF);
  _Float16* F1 = F0 + F0_ELEMS;
  _Float16* F2 = F1 + F1_ELEMS;

  // occupancy guard: cooperative 1024-block launch needs >= 4 blocks/CU
  int nb = 0;
  hipError_t qerr = hipOccupancyMaxActiveBlocksPerMultiprocessor(
      &nb, reinterpret_cast<const void*>(mega_kernel), 256, 0);
  bool use_mega = (qerr == hipSuccess && nb >= 4);

  if (use_mega) {
    MegaArgs ma;
    ma.attrs = attrs; ma.states = states; ma.rel_attrs = rel_attrs;
    ma.enc_w0 = enc_w0; ma.enc_b0 = enc_b0; ma.enc_w1 = enc_w1; ma.enc_b1 = enc_b1;
    ma.rel_b0 = rel_b0; ma.rel_b1 = rel_b1;
    ma.rel_w0 = rel_w0; ma.rel_w1 = rel_w1;
    ma.rp_w = rp_w; ma.rp_b = rp_b; ma.pp_w = pp_w; ma.pp_b = pp_b;
    ma.pred_w0 = pred_w0; ma.pred_b0 = pred_b0;
    ma.pred_w1 = pred_w1; ma.pred_b1 = pred_b1;
    ma.F0 = F0; ma.F1 = F1; ma.F2 = F2; ma.P = P;
    ma.obj0 = obj0; ma.obj1 = obj1; ma.Q0 = Q0; ma.R0 = R0;
    ma.Q1 = Q1; ma.R1 = R1; ma.part1 = part1; ma.out = out;

    void* args[] = { &ma };
    hipError_t err = hipLaunchCooperativeKernel(
        reinterpret_cast<void*>(mega_kernel), dim3(1024), dim3(256),
        args, 0, stream);
    if (err == hipSuccess) return;
  }

  // ---- fallback: proven R21 4-dispatch path (186.8 us)
  enc_qr_prep_kernel<<<NROWS_OBJ / 4, 1024, 0, stream>>>(
      attrs, states, enc_w0, enc_b0, enc_w1, enc_b1, rp_w, rp_b,
      rel_w0, rel_w1, F0, F1, F2, obj0, Q0, R0);
  rel_agg_store_mfma<<<NROWS_REL / ROWS, 256, 0, stream>>>(
      attrs, states, rel_attrs,
      F0, rel_b0, F1, rel_b1, F2,
      Q0, R0, P, part1);
  upd_qr_kernel<<<NROWS_OBJ / 4, 1024, 0, stream>>>(part1, obj0, pp_w, pp_b,
                                                    rp_w, rp_b, obj1, Q1, R1);
  aggupd_pred_kernel<<<NROWS_OBJ / 4, 1024, 0, stream>>>(P, Q1, R1, obj1,
                                                         pp_w, pp_b,
                                                         pred_w0, pred_b0,
                                                         pred_w1, pred_b1, out);
}